// Round 2
// baseline (707.932 us; speedup 1.0000x reference)
//
#include <hip/hip_runtime.h>
#include <hip/hip_bf16.h>

// out[n,m,d] = pw[l(m)] * sum_c x[n,m,c] * W[l(m)][c,d]
// N=50000, NCOMP=16, C=128. fp32 in/out. Threshold (2% of absmax) permits
// bf16 MFMA compute with fp32 accumulate.
//
// Structure: 16 per-component GEMMs [50000,128]x[128,128], MFMA 16x16x32 bf16.
// Pre-kernel bakes pw into bf16 transposed weights Wt[l][d][c] in d_ws (RNE),
// so B fragments are 16B bf16 loads (L1/L2-resident, 32 KB per l).
//
// Round-N changes vs 690us baseline:
//  - 32-bit offsets everywhere (max index 102.4M < 2^31): kills v_lshl_add_u64
//    chains, frees VGPRs (occupancy), fewer VALU issue slots.
//  - Non-temporal loads for x and non-temporal stores for out: 819 MB of
//    pure-streaming traffic no longer evicts Wt from L1/L2/L3.
//    (NOTE: __builtin_nontemporal_load needs a clang ext_vector pointer, not
//    HIP's float4 struct — use f32x4 = ext_vector_type(4) float.)
//  - Explicit one-deep software pipeline on the kk loop: next A-tile loads
//    issue before the current MFMA cluster.

using bf16 = __hip_bfloat16;
typedef short bf16x8 __attribute__((ext_vector_type(8)));  // MFMA A/B frag: 8 bf16 (4 VGPRs)
typedef float f32x4 __attribute__((ext_vector_type(4)));   // MFMA C/D frag + vec loads

#define N_NODES 50000
#define NCOMP 16
#define C 128   // C_IN == C_OUT == 128

// Pack two fp32 -> one dword holding [bf16(lo) | bf16(hi)<<16], round-to-nearest-up.
__device__ inline unsigned pack2_bf16(float lo, float hi) {
    unsigned a = __float_as_uint(lo) + 0x8000u;
    unsigned b = __float_as_uint(hi) + 0x8000u;
    // result bytes (LSB..MSB): a.b2, a.b3, b.b2, b.b3
    return __builtin_amdgcn_perm(b, a, 0x07060302u);
}

// Wt[l][d][c] = bf16(pw[l] * W[l][c][d])   (65536 elements, 128 KB in d_ws)
__global__ void transpose_w_kernel(const float* __restrict__ W,
                                   const float* __restrict__ pw,
                                   bf16* __restrict__ Wt) {
    int idx = blockIdx.x * blockDim.x + threadIdx.x;  // 0..65535
    int l = idx >> 14;
    int rem = idx & 16383;
    int d = rem >> 7;
    int c = rem & 127;
    float v = W[(l << 14) + c * C + d] * pw[l];
    Wt[(l << 14) + d * C + c] = __float2bfloat16(v);  // RNE
}

__global__ __launch_bounds__(256) void linear_sh_kernel(const float* __restrict__ x,
                                                        const bf16* __restrict__ Wt,
                                                        float* __restrict__ out) {
    // block = (m, n-tile): m = bid & 15, tile = bid >> 4 covers n in [tile*128, +128)
    const int m    = blockIdx.x & 15;
    const int tile = blockIdx.x >> 4;
    const int l    = (m >= 9) ? 3 : (m >= 4) ? 2 : (m >= 1) ? 1 : 0;
    const bf16* __restrict__ wt = Wt + (l << 14);  // Wt[l][d][c], d-major

    const int wave = threadIdx.x >> 6;   // 4 waves: rows 32w..32w+31
    const int lane = threadIdx.x & 63;
    const int lrow = lane & 15;
    const int quad = lane >> 4;

    const int n_base = tile * 128 + wave * 32;

    f32x4 acc[2][8];
#pragma unroll
    for (int g = 0; g < 2; ++g)
#pragma unroll
        for (int c8 = 0; c8 < 8; ++c8)
            acc[g][c8] = (f32x4){0.f, 0.f, 0.f, 0.f};

    // A-fragment row base offsets, 32-bit (max index 102.4M < 2^31).
    // Clamped for the n-tail; stores are guarded.
    unsigned offA[2];
#pragma unroll
    for (int g = 0; g < 2; ++g) {
        int n = n_base + g * 16 + lrow;
        if (n >= N_NODES) n = N_NODES - 1;
        offA[g] = (unsigned)(n * NCOMP + m) * C + quad * 8;  // elements; +kk*32 below
    }

    // One-deep pipeline: f0/f1[g] hold the kk-th 32-float slice (8 floats/lane).
    f32x4 f0[2], f1[2];
#pragma unroll
    for (int g = 0; g < 2; ++g) {
        f0[g] = __builtin_nontemporal_load(
            reinterpret_cast<const f32x4*>(x + offA[g]));
        f1[g] = __builtin_nontemporal_load(
            reinterpret_cast<const f32x4*>(x + offA[g] + 4));
    }

#pragma unroll
    for (int kk = 0; kk < 4; ++kk) {  // K = 128 in 4 steps of 32
        bf16x8 a[2];
#pragma unroll
        for (int g = 0; g < 2; ++g) {
            union { unsigned u[4]; bf16x8 v; } pk;
            pk.u[0] = pack2_bf16(f0[g][0], f0[g][1]);
            pk.u[1] = pack2_bf16(f0[g][2], f0[g][3]);
            pk.u[2] = pack2_bf16(f1[g][0], f1[g][1]);
            pk.u[3] = pack2_bf16(f1[g][2], f1[g][3]);
            a[g] = pk.v;
        }
        // Prefetch next kk slice before the MFMA cluster.
        if (kk < 3) {
#pragma unroll
            for (int g = 0; g < 2; ++g) {
                f0[g] = __builtin_nontemporal_load(
                    reinterpret_cast<const f32x4*>(x + offA[g] + (kk + 1) * 32));
                f1[g] = __builtin_nontemporal_load(
                    reinterpret_cast<const f32x4*>(x + offA[g] + (kk + 1) * 32 + 4));
            }
        }
#pragma unroll
        for (int c8 = 0; c8 < 8; ++c8) {
            // B[k][col]: lane holds k = kk*32 + quad*8 + j, col = c8*16 + lrow
            bf16x8 b = *reinterpret_cast<const bf16x8*>(
                wt + (c8 * 16 + lrow) * C + kk * 32 + quad * 8);
            acc[0][c8] = __builtin_amdgcn_mfma_f32_16x16x32_bf16(a[0], b, acc[0][c8], 0, 0, 0);
            acc[1][c8] = __builtin_amdgcn_mfma_f32_16x16x32_bf16(a[1], b, acc[1][c8], 0, 0, 0);
        }
    }

    // Epilogue: D layout col = lane&15, row = quad*4 + reg. pw already in Wt.
    // Non-temporal: out is written once, never re-read.
#pragma unroll
    for (int g = 0; g < 2; ++g) {
#pragma unroll
        for (int r = 0; r < 4; ++r) {
            int n = n_base + g * 16 + quad * 4 + r;
            if (n < N_NODES) {
                unsigned obase = (unsigned)(n * NCOMP + m) * C + lrow;
#pragma unroll
                for (int c8 = 0; c8 < 8; ++c8)
                    __builtin_nontemporal_store(acc[g][c8][r], out + obase + c8 * 16);
            }
        }
    }
}

extern "C" void kernel_launch(void* const* d_in, const int* in_sizes, int n_in,
                              void* d_out, int out_size, void* d_ws, size_t ws_size,
                              hipStream_t stream) {
    const float* x  = (const float*)d_in[0];   // [50000, 16, 128] fp32
    const float* W  = (const float*)d_in[1];   // [4, 128, 128] fp32
    const float* pw = (const float*)d_in[2];   // [4] fp32
    float* out = (float*)d_out;                // [50000, 16, 128] fp32
    bf16* Wt  = (bf16*)d_ws;                   // 65536 bf16 = 128 KB scratch

    // Wt[l][d][c] = bf16(pw[l] * W[l][c][d])
    transpose_w_kernel<<<256, 256, 0, stream>>>(W, pw, Wt);

    const int tiles = (N_NODES + 127) / 128;  // 391
    linear_sh_kernel<<<tiles * NCOMP, 256, 0, stream>>>(x, Wt, out);
}

// Round 3
// 702.067 us; speedup vs baseline: 1.0084x; 1.0084x over previous
//
#include <hip/hip_runtime.h>
#include <hip/hip_bf16.h>

// out[n,m,d] = pw[l(m)] * sum_c x[n,m,c] * W[l(m)][c,d]
// N=50000, NCOMP=16, C=128. fp32 in/out. Threshold (2% of absmax) permits
// bf16 MFMA compute with fp32 accumulate.
//
// Structure: 16 per-component GEMMs [50000,128]x[128,128], MFMA 16x16x32 bf16.
// Pre-kernel bakes pw into bf16 transposed weights Wt[l][d][c] in d_ws (RNE),
// so B fragments are 16B bf16 loads (L1/L2-resident, 32 KB per l).
//
// Round history:
//  - 690.3 us: baseline (prev session best).
//  - 707.9 us: +nt loads/stores +32-bit addrs +kk pipeline. REGRESSION traced
//    to nt: epilogue stores are 4x64B scattered segments per instr; L2
//    write-combining of the two 64B halves of each 128B line is what makes
//    them cheap, and nt defeats it. nt loads bought nothing (x is a 409MB
//    single-pass stream, LRU-thrashed in L3 either way).
//  - This round: REVERT nt everywhere; KEEP 32-bit offsets (kills
//    v_lshl_add_u64 chains) and the one-deep kk software pipeline.

using bf16 = __hip_bfloat16;
typedef short bf16x8 __attribute__((ext_vector_type(8)));  // MFMA A/B frag: 8 bf16 (4 VGPRs)
typedef float f32x4 __attribute__((ext_vector_type(4)));   // MFMA C/D frag + vec loads

#define N_NODES 50000
#define NCOMP 16
#define C 128   // C_IN == C_OUT == 128

// Pack two fp32 -> one dword holding [bf16(lo) | bf16(hi)<<16], round-to-nearest-up.
__device__ inline unsigned pack2_bf16(float lo, float hi) {
    unsigned a = __float_as_uint(lo) + 0x8000u;
    unsigned b = __float_as_uint(hi) + 0x8000u;
    // result bytes (LSB..MSB): a.b2, a.b3, b.b2, b.b3
    return __builtin_amdgcn_perm(b, a, 0x07060302u);
}

// Wt[l][d][c] = bf16(pw[l] * W[l][c][d])   (65536 elements, 128 KB in d_ws)
__global__ void transpose_w_kernel(const float* __restrict__ W,
                                   const float* __restrict__ pw,
                                   bf16* __restrict__ Wt) {
    int idx = blockIdx.x * blockDim.x + threadIdx.x;  // 0..65535
    int l = idx >> 14;
    int rem = idx & 16383;
    int d = rem >> 7;
    int c = rem & 127;
    float v = W[(l << 14) + c * C + d] * pw[l];
    Wt[(l << 14) + d * C + c] = __float2bfloat16(v);  // RNE
}

__global__ __launch_bounds__(256) void linear_sh_kernel(const float* __restrict__ x,
                                                        const bf16* __restrict__ Wt,
                                                        float* __restrict__ out) {
    // block = (m, n-tile): m = bid & 15, tile = bid >> 4 covers n in [tile*128, +128)
    const int m    = blockIdx.x & 15;
    const int tile = blockIdx.x >> 4;
    const int l    = (m >= 9) ? 3 : (m >= 4) ? 2 : (m >= 1) ? 1 : 0;
    const bf16* __restrict__ wt = Wt + (l << 14);  // Wt[l][d][c], d-major

    const int wave = threadIdx.x >> 6;   // 4 waves: rows 32w..32w+31
    const int lane = threadIdx.x & 63;
    const int lrow = lane & 15;
    const int quad = lane >> 4;

    const int n_base = tile * 128 + wave * 32;

    f32x4 acc[2][8];
#pragma unroll
    for (int g = 0; g < 2; ++g)
#pragma unroll
        for (int c8 = 0; c8 < 8; ++c8)
            acc[g][c8] = (f32x4){0.f, 0.f, 0.f, 0.f};

    // A-fragment row base offsets, 32-bit (max index 102.4M < 2^31).
    // Clamped for the n-tail; stores are guarded.
    unsigned offA[2];
#pragma unroll
    for (int g = 0; g < 2; ++g) {
        int n = n_base + g * 16 + lrow;
        if (n >= N_NODES) n = N_NODES - 1;
        offA[g] = (unsigned)(n * NCOMP + m) * C + quad * 8;  // elements; +kk*32 below
    }

    // One-deep pipeline: f0/f1[g] hold the kk-th 32-float slice (8 floats/lane).
    f32x4 f0[2], f1[2];
#pragma unroll
    for (int g = 0; g < 2; ++g) {
        f0[g] = *reinterpret_cast<const f32x4*>(x + offA[g]);
        f1[g] = *reinterpret_cast<const f32x4*>(x + offA[g] + 4);
    }

#pragma unroll
    for (int kk = 0; kk < 4; ++kk) {  // K = 128 in 4 steps of 32
        bf16x8 a[2];
#pragma unroll
        for (int g = 0; g < 2; ++g) {
            union { unsigned u[4]; bf16x8 v; } pk;
            pk.u[0] = pack2_bf16(f0[g][0], f0[g][1]);
            pk.u[1] = pack2_bf16(f0[g][2], f0[g][3]);
            pk.u[2] = pack2_bf16(f1[g][0], f1[g][1]);
            pk.u[3] = pack2_bf16(f1[g][2], f1[g][3]);
            a[g] = pk.v;
        }
        // Prefetch next kk slice before the MFMA cluster.
        if (kk < 3) {
#pragma unroll
            for (int g = 0; g < 2; ++g) {
                f0[g] = *reinterpret_cast<const f32x4*>(x + offA[g] + (kk + 1) * 32);
                f1[g] = *reinterpret_cast<const f32x4*>(x + offA[g] + (kk + 1) * 32 + 4);
            }
        }
#pragma unroll
        for (int c8 = 0; c8 < 8; ++c8) {
            // B[k][col]: lane holds k = kk*32 + quad*8 + j, col = c8*16 + lrow
            bf16x8 b = *reinterpret_cast<const bf16x8*>(
                wt + (c8 * 16 + lrow) * C + kk * 32 + quad * 8);
            acc[0][c8] = __builtin_amdgcn_mfma_f32_16x16x32_bf16(a[0], b, acc[0][c8], 0, 0, 0);
            acc[1][c8] = __builtin_amdgcn_mfma_f32_16x16x32_bf16(a[1], b, acc[1][c8], 0, 0, 0);
        }
    }

    // Epilogue: D layout col = lane&15, row = quad*4 + reg. pw already in Wt.
    // Plain stores: adjacent c8 iterations hit the two 64B halves of each
    // 128B line; L2 write-combines them (nt defeated this — see header).
#pragma unroll
    for (int g = 0; g < 2; ++g) {
#pragma unroll
        for (int r = 0; r < 4; ++r) {
            int n = n_base + g * 16 + quad * 4 + r;
            if (n < N_NODES) {
                unsigned obase = (unsigned)(n * NCOMP + m) * C + lrow;
#pragma unroll
                for (int c8 = 0; c8 < 8; ++c8)
                    out[obase + c8 * 16] = acc[g][c8][r];
            }
        }
    }
}

extern "C" void kernel_launch(void* const* d_in, const int* in_sizes, int n_in,
                              void* d_out, int out_size, void* d_ws, size_t ws_size,
                              hipStream_t stream) {
    const float* x  = (const float*)d_in[0];   // [50000, 16, 128] fp32
    const float* W  = (const float*)d_in[1];   // [4, 128, 128] fp32
    const float* pw = (const float*)d_in[2];   // [4] fp32
    float* out = (float*)d_out;                // [50000, 16, 128] fp32
    bf16* Wt  = (bf16*)d_ws;                   // 65536 bf16 = 128 KB scratch

    // Wt[l][d][c] = bf16(pw[l] * W[l][c][d])
    transpose_w_kernel<<<256, 256, 0, stream>>>(W, pw, Wt);

    const int tiles = (N_NODES + 127) / 128;  // 391
    linear_sh_kernel<<<tiles * NCOMP, 256, 0, stream>>>(x, Wt, out);
}

// Round 4
// 689.065 us; speedup vs baseline: 1.0274x; 1.0189x over previous
//
#include <hip/hip_runtime.h>
#include <hip/hip_bf16.h>

// out[n,m,d] = pw[l(m)] * sum_c x[n,m,c] * W[l(m)][c,d]
// N=50000, NCOMP=16, C=128. fp32 in/out (NaN in round 1 proved inputs are fp32,
// not bf16 — reading fp32 as bf16 makes NaN bit patterns). Threshold (2% of
// absmax) permits bf16 MFMA compute with fp32 accumulate.
//
// Structure: 16 per-component GEMMs [50000,128]x[128,128], MFMA 16x16x32 bf16.
// Pre-kernel bakes pw into bf16 transposed weights Wt[l][d][c] in d_ws (RNE),
// so B fragments are 16B bf16 loads (L1-resident, 32 KB per l). A fragments:
// fp32 loads from x, packed to bf16 in-register (round-to-nearest via +0x8000
// then v_perm_b32). No LDS, no __syncthreads.
//
// Session post-mortem (4 holds):
//  - 690.3 us baseline (this source, reproduced 691.4/690.3 across sessions).
//  - +nt hints: 707.9 (nt defeats L2 write-combining of the 4x64B scattered
//    epilogue segments; nt loads buy nothing on a single-pass 409MB stream).
//  - 32-bit offsets + explicit one-deep kk prefetch, no nt: 702.1 even with
//    faster fills that hold — holding f0/f1 live across the MFMA cluster adds
//    ~16 VGPRs and defeats the compiler's own (better) schedule.
//  => REVERTED to baseline verbatim. Accounting: timed region = ~516us harness
//    poison fills (2x1.6GB at 79% HBM peak, their own ceiling) + ~3us transpose
//    + ~172us linear kernel (819.2MB mandatory fp32 traffic -> 130us floor at
//    6.3TB/s). Structural floor ~650us vs 690 measured: <6% total headroom,
//    and both attempts to claim it regressed. This is the roofline.

using bf16 = __hip_bfloat16;
typedef short bf16x8 __attribute__((ext_vector_type(8)));  // MFMA A/B frag: 8 bf16 (4 VGPRs)
typedef float f32x4 __attribute__((ext_vector_type(4)));   // MFMA C/D frag

#define N_NODES 50000
#define NCOMP 16
#define C 128   // C_IN == C_OUT == 128

// Pack two fp32 -> one dword holding [bf16(lo) | bf16(hi)<<16], round-to-nearest.
__device__ inline unsigned pack2_bf16(float lo, float hi) {
    unsigned a = __float_as_uint(lo) + 0x8000u;
    unsigned b = __float_as_uint(hi) + 0x8000u;
    // result bytes (LSB..MSB): a.b2, a.b3, b.b2, b.b3
    return __builtin_amdgcn_perm(b, a, 0x07060302u);
}

// Wt[l][d][c] = bf16(pw[l] * W[l][c][d])   (65536 elements, 128 KB in d_ws)
__global__ void transpose_w_kernel(const float* __restrict__ W,
                                   const float* __restrict__ pw,
                                   bf16* __restrict__ Wt) {
    int idx = blockIdx.x * blockDim.x + threadIdx.x;  // 0..65535
    int l = idx >> 14;
    int rem = idx & 16383;
    int d = rem >> 7;
    int c = rem & 127;
    float v = W[(l << 14) + c * C + d] * pw[l];
    Wt[(l << 14) + d * C + c] = __float2bfloat16(v);  // RNE
}

__global__ __launch_bounds__(256) void linear_sh_kernel(const float* __restrict__ x,
                                                        const bf16* __restrict__ Wt,
                                                        float* __restrict__ out) {
    // block = (m, n-tile): m = bid & 15, tile = bid >> 4 covers n in [tile*128, +128)
    const int m    = blockIdx.x & 15;
    const int tile = blockIdx.x >> 4;
    const int l    = (m >= 9) ? 3 : (m >= 4) ? 2 : (m >= 1) ? 1 : 0;
    const bf16* __restrict__ wt = Wt + (l << 14);  // Wt[l][d][c], d-major

    const int wave = threadIdx.x >> 6;   // 4 waves: rows 32w..32w+31
    const int lane = threadIdx.x & 63;
    const int lrow = lane & 15;
    const int quad = lane >> 4;

    const int n_base = tile * 128 + wave * 32;

    f32x4 acc[2][8];
#pragma unroll
    for (int g = 0; g < 2; ++g)
#pragma unroll
        for (int c8 = 0; c8 < 8; ++c8)
            acc[g][c8] = (f32x4){0.f, 0.f, 0.f, 0.f};

    // A-fragment row base offsets (clamped for the n-tail; stores are guarded)
    long offA[2];
#pragma unroll
    for (int g = 0; g < 2; ++g) {
        int n = n_base + g * 16 + lrow;
        if (n >= N_NODES) n = N_NODES - 1;
        offA[g] = (long)(n * NCOMP + m) * C + quad * 8;  // elements; +kk*32 below
    }

    for (int kk = 0; kk < 4; ++kk) {  // K = 128 in 4 steps of 32
        bf16x8 a[2];
#pragma unroll
        for (int g = 0; g < 2; ++g) {
            const float4 f0 = *reinterpret_cast<const float4*>(x + offA[g] + kk * 32);
            const float4 f1 = *reinterpret_cast<const float4*>(x + offA[g] + kk * 32 + 4);
            union { unsigned u[4]; bf16x8 v; } pk;
            pk.u[0] = pack2_bf16(f0.x, f0.y);
            pk.u[1] = pack2_bf16(f0.z, f0.w);
            pk.u[2] = pack2_bf16(f1.x, f1.y);
            pk.u[3] = pack2_bf16(f1.z, f1.w);
            a[g] = pk.v;
        }
#pragma unroll
        for (int c8 = 0; c8 < 8; ++c8) {
            // B[k][col]: lane holds k = kk*32 + quad*8 + j, col = c8*16 + lrow
            bf16x8 b = *reinterpret_cast<const bf16x8*>(
                wt + (c8 * 16 + lrow) * C + kk * 32 + quad * 8);
            acc[0][c8] = __builtin_amdgcn_mfma_f32_16x16x32_bf16(a[0], b, acc[0][c8], 0, 0, 0);
            acc[1][c8] = __builtin_amdgcn_mfma_f32_16x16x32_bf16(a[1], b, acc[1][c8], 0, 0, 0);
        }
    }

    // Epilogue: D layout col = lane&15, row = quad*4 + reg. pw already in Wt.
#pragma unroll
    for (int g = 0; g < 2; ++g) {
#pragma unroll
        for (int r = 0; r < 4; ++r) {
            int n = n_base + g * 16 + quad * 4 + r;
            if (n < N_NODES) {
                long obase = (long)(n * NCOMP + m) * C;
#pragma unroll
                for (int c8 = 0; c8 < 8; ++c8)
                    out[obase + c8 * 16 + lrow] = acc[g][c8][r];
            }
        }
    }
}

extern "C" void kernel_launch(void* const* d_in, const int* in_sizes, int n_in,
                              void* d_out, int out_size, void* d_ws, size_t ws_size,
                              hipStream_t stream) {
    const float* x  = (const float*)d_in[0];   // [50000, 16, 128] fp32
    const float* W  = (const float*)d_in[1];   // [4, 128, 128] fp32
    const float* pw = (const float*)d_in[2];   // [4] fp32
    float* out = (float*)d_out;                // [50000, 16, 128] fp32
    bf16* Wt  = (bf16*)d_ws;                   // 65536 bf16 = 128 KB scratch

    // Wt[l][d][c] = bf16(pw[l] * W[l][c][d])
    transpose_w_kernel<<<256, 256, 0, stream>>>(W, pw, Wt);

    const int tiles = (N_NODES + 127) / 128;  // 391
    linear_sh_kernel<<<tiles * NCOMP, 256, 0, stream>>>(x, Wt, out);
}